// Round 1
// 3853.186 us; speedup vs baseline: 1.0091x; 1.0091x over previous
//
#include <hip/hip_runtime.h>
#include <math.h>

#define B_     128
#define L_     100
#define HID_   256
#define IND_   160
#define NCLASS 19
#define CAPD   16
#define NI     1600      // L_ * NUM_CAPS
#define OD     304       // NCLASS * CAPD
#define ENTITY 68

// ---------------------------------------------------------------------------
// Phase 0: embedding gather -> emb [b*L_+t][160]
// ---------------------------------------------------------------------------
__global__ void emb_gather(const int* __restrict__ word, const int* __restrict__ tag,
                           const int* __restrict__ pos1, const int* __restrict__ pos2,
                           const float* __restrict__ we, const float* __restrict__ te,
                           const float* __restrict__ p1e, const float* __restrict__ p2e,
                           float* __restrict__ emb)
{
    int idx = blockIdx.x * 256 + threadIdx.x;          // exactly B_*L_*IND_ threads
    int bt = idx / IND_;
    int k  = idx - bt * IND_;
    float v;
    if (k < 100)      v = we[word[bt] * 100 + k];
    else if (k < 120) v = te[tag[bt] * 20 + (k - 100)];
    else if (k < 140) v = p1e[pos1[bt] * 20 + (k - 120)];
    else              v = p2e[pos2[bt] * 20 + (k - 140)];
    emb[idx] = v;
}

// ---------------------------------------------------------------------------
// Phase 1: input-gate GEMM.
// xg layout: [dir][t][bpair(64)][gj(1024)][2]  (b = bpair*2 + c)
// so the scan's per-step gate load is a coalesced dwordx2 over lanes=j.
// ---------------------------------------------------------------------------
__global__ void __launch_bounds__(256) gemm_xg(
    const float* __restrict__ emb,
    const float* __restrict__ wihf, const float* __restrict__ bihf, const float* __restrict__ bhhf,
    const float* __restrict__ wihb, const float* __restrict__ bihb, const float* __restrict__ bhhb,
    float* __restrict__ xg)
{
    int gt  = blockIdx.x;
    int t   = blockIdx.y;
    int dir = blockIdx.z;
    const float* w  = dir ? wihb : wihf;
    const float* bi = dir ? bihb : bihf;
    const float* bh = dir ? bhhb : bhhf;
    int gj0 = gt * 128;

    __shared__ float wsh[32][132];   // [k][gj], padded
    __shared__ float esh[32][132];   // [k][b],  padded

    int tid = threadIdx.x;
    int tx = tid & 15, ty = tid >> 4;

    float acc[8][8];
    #pragma unroll
    for (int i = 0; i < 8; ++i)
        #pragma unroll
        for (int j = 0; j < 8; ++j) acc[i][j] = 0.f;

    for (int k0 = 0; k0 < IND_; k0 += 32) {
        __syncthreads();
        #pragma unroll
        for (int m = 0; m < 16; ++m) {
            int e = m * 256 + tid;        // 0..4095
            int k = e & 31, g = e >> 5;   // g: row (gj or b)
            wsh[k][g] = w[(gj0 + g) * IND_ + k0 + k];
            esh[k][g] = emb[(g * L_ + t) * IND_ + k0 + k];
        }
        __syncthreads();
        #pragma unroll
        for (int k = 0; k < 32; ++k) {
            float wv[8], ev[8];
            #pragma unroll
            for (int q = 0; q < 8; ++q) wv[q] = wsh[k][ty * 8 + q];
            #pragma unroll
            for (int q = 0; q < 8; ++q) ev[q] = esh[k][tx * 8 + q];
            #pragma unroll
            for (int i = 0; i < 8; ++i)
                #pragma unroll
                for (int j = 0; j < 8; ++j) acc[i][j] = fmaf(wv[i], ev[j], acc[i][j]);
        }
    }
    #pragma unroll
    for (int i = 0; i < 8; ++i) {
        int gj = gj0 + ty * 8 + i;
        float bias = bi[gj] + bh[gj];
        #pragma unroll
        for (int j = 0; j < 8; ++j) {
            int b = tx * 8 + j;
            xg[((((size_t)dir * L_ + t) * 64 + (b >> 1)) * 1024 + gj) * 2 + (b & 1)]
                = acc[i][j] + bias;
        }
    }
}

// ---------------------------------------------------------------------------
// Phase 2: BiLSTM scan. Block = (dir, b-pair): 128 blocks x 1024 threads.
// Each thread owns ONE gate row j (of 1024) for 2 batch columns -> 16 waves/CU
// (4/SIMD) to hide the L2 weight-stream latency (was 4 waves/CU, 1/SIMD,
// load-latency serialized at 30us/step). Gate coupling goes through an 8KB
// LDS gs buffer; threads<512 apply nonlinearities and keep c in registers.
// Floors: compute ~1.7us/step, L2 weight stream ~3.7us/step (128MB/step).
// ---------------------------------------------------------------------------
__global__ void __launch_bounds__(1024, 4) lstm_scan_c(
    const float* __restrict__ xg, const float* __restrict__ whhf,
    const float* __restrict__ whhb, float* __restrict__ xf, float* __restrict__ xb)
{
    int blk = blockIdx.x;
    int dir = blk >> 6;            // 0..1
    int bp  = blk & 63;            // b-pair index
    int j   = threadIdx.x;         // 0..1023 = gate row (gate = j>>8, hid = j&255)

    const float* whh = dir ? whhb : whhf;
    const float4* wrow = (const float4*)(whh + (size_t)j * HID_);  // row j, 64 float4
    float* xo = dir ? xb : xf;

    __shared__ float hs[HID_ * 2];      // [hid][bsub], 2KB; read as float4 (2 hid x 2 b)
    __shared__ float gs[1024 * 2];      // [gate][hid][bsub] = gate*512 + hid*2 + bs, 8KB

    if (j < 512) hs[j] = 0.f;
    float c = 0.f;                      // cell state for (hid=j>>1, bs=j&1), j<512 only
    __syncthreads();

    int gbase = (j >> 8) * 512 + (j & 255) * 2;   // gs write base for row j

    for (int t = 0; t < L_; ++t) {
        int slot = dir ? (L_ - 1 - t) : t;
        // xg gate preload (consumed after the k-loop -> fully hidden)
        const float* xbase = xg + (((size_t)dir * L_ + slot) * 64 + bp) * 2048;
        float2 gin = *(const float2*)(xbase + j * 2);

        float a0 = 0.f, a1 = 0.f;
        const float4* hp = (const float4*)hs;     // hp[q] = {h[2q]b0,h[2q]b1,h[2q+1]b0,h[2q+1]b1}
        #pragma unroll 4
        for (int k4 = 0; k4 < HID_ / 4; ++k4) {
            float4 wv = wrow[k4];                 // 4 k of weights (L2-resident stream)
            float4 h0 = hp[k4 * 2];               // broadcast reads (uniform addr per wave)
            float4 h1 = hp[k4 * 2 + 1];
            a0 = fmaf(wv.x, h0.x, a0); a1 = fmaf(wv.x, h0.y, a1);
            a0 = fmaf(wv.y, h0.z, a0); a1 = fmaf(wv.y, h0.w, a1);
            a0 = fmaf(wv.z, h1.x, a0); a1 = fmaf(wv.z, h1.y, a1);
            a0 = fmaf(wv.w, h1.z, a0); a1 = fmaf(wv.w, h1.w, a1);
        }
        *(float2*)(gs + gbase) = make_float2(a0 + gin.x, a1 + gin.y);
        __syncthreads();   // gs visible; all hs reads of this step complete

        if (j < 512) {     // j = hid*2 + bs
            float i_ = 1.f / (1.f + expf(-gs[j]));            // gate 0
            float f_ = 1.f / (1.f + expf(-gs[512 + j]));      // gate 1
            float g_ = tanhf(gs[1024 + j]);                   // gate 2
            float o_ = 1.f / (1.f + expf(-gs[1536 + j]));     // gate 3
            c = f_ * c + i_ * g_;
            float h = o_ * tanhf(c);
            hs[j] = h;
            int hid = j >> 1, bs = j & 1;
            xo[((size_t)slot * HID_ + hid) * B_ + bp * 2 + bs] = h;
        }
        __syncthreads();   // hs writes visible before next step's reads
    }
}

__global__ void x_add(const float* __restrict__ xf, const float* __restrict__ xb,
                      float* __restrict__ x)
{
    int idx = blockIdx.x * 256 + threadIdx.x;   // exactly L_*HID_*B_ threads
    x[idx] = xf[idx] + xb[idx];
}

// ---------------------------------------------------------------------------
// Phase 3: entity features, attention, primary capsules
// ---------------------------------------------------------------------------
__global__ void find_entity(const int* __restrict__ pos1, const int* __restrict__ pos2,
                            int* __restrict__ e)
{
    int b = threadIdx.x;
    int e1 = 0, e2 = 0;
    for (int l = L_ - 1; l >= 0; --l) if (pos1[b * L_ + l] == ENTITY) e1 = l;
    for (int l = L_ - 1; l >= 0; --l) if (pos2[b * L_ + l] == ENTITY) e2 = l;
    e[b] = e1; e[B_ + b] = e2;
}

__global__ void compute_he(const float* __restrict__ x, const int* __restrict__ e,
                           float* __restrict__ he)
{
    int j = blockIdx.x, b = threadIdx.x;
    int e1 = e[b], e2 = e[B_ + b];
    he[j * B_ + b] = x[((size_t)e1 * HID_ + j) * B_ + b] + x[((size_t)e2 * HID_ + j) * B_ + b];
}

__global__ void att_logits(const float* __restrict__ x, const float* __restrict__ he,
                           float* __restrict__ logits)
{
    int l = blockIdx.x, b = threadIdx.x;
    float acc = 0.f;
    for (int j = 0; j < HID_; ++j)
        acc = fmaf(x[((size_t)l * HID_ + j) * B_ + b], he[j * B_ + b], acc);
    logits[l * B_ + b] = acc;
}

__global__ void att_softmax(const float* __restrict__ logits, float* __restrict__ att)
{
    int b = threadIdx.x;
    float m = -1e30f;
    for (int l = 0; l < L_; ++l) m = fmaxf(m, logits[l * B_ + b]);
    float s = 0.f;
    for (int l = 0; l < L_; ++l) s += expf(logits[l * B_ + b] - m);
    float inv = 1.f / s;
    for (int l = 0; l < L_; ++l) att[l * B_ + b] = expf(logits[l * B_ + b] - m) * inv;
}

// primary capsules: u[i][b][c], squashed
__global__ void u_squash(const float* __restrict__ x, float* __restrict__ u)
{
    int i = blockIdx.x, b = threadIdx.x;
    int l = i >> 4, cap = i & 15;
    float vals[16]; float n2 = 0.f;
    #pragma unroll
    for (int c2 = 0; c2 < 16; ++c2) {
        float v = x[((size_t)l * HID_ + cap * 16 + c2) * B_ + b];
        vals[c2] = v; n2 = fmaf(v, v, n2);
    }
    float f = (n2 / (1.f + n2)) / sqrtf(n2 + 1e-9f);
    #pragma unroll
    for (int c2 = 0; c2 < 16; ++c2)
        u[((size_t)i * B_ + b) * 16 + c2] = vals[c2] * f;
}

// ---------------------------------------------------------------------------
// Phase 4: routing
// ---------------------------------------------------------------------------
__global__ void bb_init(const float* __restrict__ br, float* __restrict__ bb)
{
    int idx = blockIdx.x * 256 + threadIdx.x;   // exactly B_*NI*NCLASS threads
    bb[idx] = br[idx % (NI * NCLASS)];
}

__global__ void __launch_bounds__(320) s_pass(
    const float* __restrict__ u, const float* __restrict__ W,
    const float* __restrict__ bb, const float* __restrict__ att,
    float* __restrict__ partial)
{
    int ic = blockIdx.x, bt = blockIdx.y;
    int i0 = ic * 16, b0 = bt * 16;
    __shared__ float C[16][16][20];   // [bl][il][o], padded
    int tid = threadIdx.x;
    if (tid < 256) {
        int bl = tid >> 4, il = tid & 15;
        int b = b0 + bl, i = i0 + il;
        const float* bbp = bb + ((size_t)b * NI + i) * NCLASS;
        float m = bbp[0];
        #pragma unroll
        for (int o = 1; o < NCLASS; ++o) m = fmaxf(m, bbp[o]);
        float s = 0.f; float e[NCLASS];
        #pragma unroll
        for (int o = 0; o < NCLASS; ++o) { e[o] = expf(bbp[o] - m); s += e[o]; }
        float al = att[(i >> 4) * B_ + b] / s;
        #pragma unroll
        for (int o = 0; o < NCLASS; ++o) C[bl][il][o] = e[o] * al;
    }
    __syncthreads();
    if (tid >= OD) return;
    int od = tid, o = od >> 4;
    float acc[16];
    #pragma unroll
    for (int bl = 0; bl < 16; ++bl) acc[bl] = 0.f;
    for (int il = 0; il < 16; ++il) {
        int i = i0 + il;
        const float* wp = W + (size_t)i * 16 * OD + od;
        float w[16];
        #pragma unroll
        for (int c2 = 0; c2 < 16; ++c2) w[c2] = wp[c2 * OD];     // coalesced over od
        const float* up = u + ((size_t)i * B_ + b0) * 16;        // uniform -> s_load
        #pragma unroll
        for (int bl = 0; bl < 16; ++bl) {
            float uh = 0.f;
            #pragma unroll
            for (int c2 = 0; c2 < 16; ++c2) uh = fmaf(up[bl * 16 + c2], w[c2], uh);
            acc[bl] = fmaf(C[bl][il][o], uh, acc[bl]);
        }
    }
    #pragma unroll
    for (int bl = 0; bl < 16; ++bl)
        partial[((size_t)ic * B_ + b0 + bl) * OD + od] = acc[bl];
}

__global__ void s_reduce(const float* __restrict__ partial, float* __restrict__ s)
{
    int idx = blockIdx.x * 256 + threadIdx.x;   // exactly B_*OD threads
    int b = idx / OD, od = idx - b * OD;
    float acc = 0.f;
    for (int ic = 0; ic < 100; ++ic) acc += partial[((size_t)ic * B_ + b) * OD + od];
    s[idx] = acc;
}

__global__ void squash_v(const float* __restrict__ s, float* __restrict__ v,
                         float* __restrict__ out, int write_out)
{
    int idx = blockIdx.x * 256 + threadIdx.x;
    if (idx >= B_ * NCLASS) return;
    const float* sp = s + (size_t)idx * 16;     // b*304 + o*16 == idx*16
    float vals[16]; float n2 = 0.f;
    #pragma unroll
    for (int d = 0; d < 16; ++d) { vals[d] = sp[d]; n2 = fmaf(vals[d], vals[d], n2); }
    float f = (n2 / (1.f + n2)) / sqrtf(n2 + 1e-9f);
    float n2v = 0.f;
    #pragma unroll
    for (int d = 0; d < 16; ++d) {
        float vv = vals[d] * f;
        v[(size_t)idx * 16 + d] = vv;
        n2v = fmaf(vv, vv, n2v);
    }
    if (write_out) out[idx] = sqrtf(n2v + 1e-9f);
}

__global__ void __launch_bounds__(320) bb_pass(
    const float* __restrict__ u, const float* __restrict__ W,
    const float* __restrict__ v, float* __restrict__ bb)
{
    int ic = blockIdx.x, bt = blockIdx.y;
    int i0 = ic * 16, b0 = bt * 16;
    int tid = threadIdx.x;
    if (tid >= OD) return;
    int od = tid, o = od >> 4, d = od & 15;
    float vv[16];
    #pragma unroll
    for (int bl = 0; bl < 16; ++bl) vv[bl] = v[(size_t)(b0 + bl) * OD + od];
    for (int il = 0; il < 16; ++il) {
        int i = i0 + il;
        const float* wp = W + (size_t)i * 16 * OD + od;
        float w[16];
        #pragma unroll
        for (int c2 = 0; c2 < 16; ++c2) w[c2] = wp[c2 * OD];
        const float* up = u + ((size_t)i * B_ + b0) * 16;
        #pragma unroll
        for (int bl = 0; bl < 16; ++bl) {
            float uh = 0.f;
            #pragma unroll
            for (int c2 = 0; c2 < 16; ++c2) uh = fmaf(up[bl * 16 + c2], w[c2], uh);
            float p = uh * vv[bl];
            p += __shfl_xor(p, 1);
            p += __shfl_xor(p, 2);
            p += __shfl_xor(p, 4);
            p += __shfl_xor(p, 8);
            if (d == 0) bb[((size_t)(b0 + bl) * NI + i) * NCLASS + o] += p;
        }
    }
}

// ---------------------------------------------------------------------------
extern "C" void kernel_launch(void* const* d_in, const int* in_sizes, int n_in,
                              void* d_out, int out_size, void* d_ws, size_t ws_size,
                              hipStream_t stream)
{
    (void)in_sizes; (void)n_in; (void)out_size; (void)ws_size;
    const int*   word = (const int*)d_in[0];
    const int*   tag  = (const int*)d_in[1];
    const int*   pos1 = (const int*)d_in[2];
    const int*   pos2 = (const int*)d_in[3];
    const float* we   = (const float*)d_in[4];
    const float* te   = (const float*)d_in[5];
    const float* p1e  = (const float*)d_in[6];
    const float* p2e  = (const float*)d_in[7];
    const float* wihf = (const float*)d_in[8];
    const float* whhf = (const float*)d_in[9];
    const float* bihf = (const float*)d_in[10];
    const float* bhhf = (const float*)d_in[11];
    const float* wihb = (const float*)d_in[12];
    const float* whhb = (const float*)d_in[13];
    const float* bihb = (const float*)d_in[14];
    const float* bhhb = (const float*)d_in[15];
    const float* Wc   = (const float*)d_in[16];
    const float* br   = (const float*)d_in[17];

    float* wsp    = (float*)d_ws;
    float* emb    = wsp;                       //  2,048,000
    float* xg     = wsp + 2048000;             // 26,214,400
    float* xf     = xg + 26214400;             //  3,276,800
    float* xb     = xf + 3276800;              //  3,276,800
    float* he     = xb + 3276800;              //     32,768
    float* logits = he + 32768;                //     12,800
    float* att    = logits + 12800;            //     12,800
    int*   e      = (int*)(att + 12800);       //        256 ints
    // post-scan buffers alias the (dead-after-scan) xg region
    float* x    = xg;                          //  3,276,800
    float* u    = xg + 3276800;                //  3,276,800
    float* bb   = xg + 6553600;                //  3,891,200
    float* part = xg + 10444800;               //  3,891,200
    float* s    = xg + 14336000;               //     38,912
    float* v    = s + 38912;                   //     38,912
    float* out  = (float*)d_out;

    emb_gather<<<8000, 256, 0, stream>>>(word, tag, pos1, pos2, we, te, p1e, p2e, emb);
    gemm_xg<<<dim3(8, 100, 2), 256, 0, stream>>>(emb, wihf, bihf, bhhf, wihb, bihb, bhhb, xg);
    lstm_scan_c<<<128, 1024, 0, stream>>>(xg, whhf, whhb, xf, xb);
    x_add<<<12800, 256, 0, stream>>>(xf, xb, x);
    find_entity<<<1, 128, 0, stream>>>(pos1, pos2, e);
    compute_he<<<256, 128, 0, stream>>>(x, e, he);
    att_logits<<<100, 128, 0, stream>>>(x, he, logits);
    att_softmax<<<1, 128, 0, stream>>>(logits, att);
    u_squash<<<1600, 128, 0, stream>>>(x, u);
    bb_init<<<15200, 256, 0, stream>>>(br, bb);
    for (int it = 0; it < 3; ++it) {
        s_pass<<<dim3(100, 8), 320, 0, stream>>>(u, Wc, bb, att, part);
        s_reduce<<<152, 256, 0, stream>>>(part, s);
        squash_v<<<10, 256, 0, stream>>>(s, v, out, (it == 2) ? 1 : 0);
        if (it < 2) bb_pass<<<dim3(100, 8), 320, 0, stream>>>(u, Wc, v, bb);
    }
}

// Round 2
// 1805.093 us; speedup vs baseline: 2.1541x; 2.1346x over previous
//
#include <hip/hip_runtime.h>
#include <math.h>

#define B_     128
#define L_     100
#define HID_   256
#define IND_   160
#define NCLASS 19
#define CAPD   16
#define NI     1600      // L_ * NUM_CAPS
#define OD     304       // NCLASS * CAPD
#define ENTITY 68

// ---------------------------------------------------------------------------
// Phase 0: embedding gather -> emb [b*L_+t][160]
// ---------------------------------------------------------------------------
__global__ void emb_gather(const int* __restrict__ word, const int* __restrict__ tag,
                           const int* __restrict__ pos1, const int* __restrict__ pos2,
                           const float* __restrict__ we, const float* __restrict__ te,
                           const float* __restrict__ p1e, const float* __restrict__ p2e,
                           float* __restrict__ emb)
{
    int idx = blockIdx.x * 256 + threadIdx.x;          // exactly B_*L_*IND_ threads
    int bt = idx / IND_;
    int k  = idx - bt * IND_;
    float v;
    if (k < 100)      v = we[word[bt] * 100 + k];
    else if (k < 120) v = te[tag[bt] * 20 + (k - 100)];
    else if (k < 140) v = p1e[pos1[bt] * 20 + (k - 120)];
    else              v = p2e[pos2[bt] * 20 + (k - 140)];
    emb[idx] = v;
}

// ---------------------------------------------------------------------------
// Phase 1: input-gate GEMM.
// xg layout: [dir][t][bpair(64)][gj(1024)][2]  (b = bpair*2 + c)
// so the scan's per-step gate load is a coalesced dwordx2 over lanes=j.
// ---------------------------------------------------------------------------
__global__ void __launch_bounds__(256) gemm_xg(
    const float* __restrict__ emb,
    const float* __restrict__ wihf, const float* __restrict__ bihf, const float* __restrict__ bhhf,
    const float* __restrict__ wihb, const float* __restrict__ bihb, const float* __restrict__ bhhb,
    float* __restrict__ xg)
{
    int gt  = blockIdx.x;
    int t   = blockIdx.y;
    int dir = blockIdx.z;
    const float* w  = dir ? wihb : wihf;
    const float* bi = dir ? bihb : bihf;
    const float* bh = dir ? bhhb : bhhf;
    int gj0 = gt * 128;

    __shared__ float wsh[32][132];   // [k][gj], padded
    __shared__ float esh[32][132];   // [k][b],  padded

    int tid = threadIdx.x;
    int tx = tid & 15, ty = tid >> 4;

    float acc[8][8];
    #pragma unroll
    for (int i = 0; i < 8; ++i)
        #pragma unroll
        for (int j = 0; j < 8; ++j) acc[i][j] = 0.f;

    for (int k0 = 0; k0 < IND_; k0 += 32) {
        __syncthreads();
        #pragma unroll
        for (int m = 0; m < 16; ++m) {
            int e = m * 256 + tid;        // 0..4095
            int k = e & 31, g = e >> 5;   // g: row (gj or b)
            wsh[k][g] = w[(gj0 + g) * IND_ + k0 + k];
            esh[k][g] = emb[(g * L_ + t) * IND_ + k0 + k];
        }
        __syncthreads();
        #pragma unroll
        for (int k = 0; k < 32; ++k) {
            float wv[8], ev[8];
            #pragma unroll
            for (int q = 0; q < 8; ++q) wv[q] = wsh[k][ty * 8 + q];
            #pragma unroll
            for (int q = 0; q < 8; ++q) ev[q] = esh[k][tx * 8 + q];
            #pragma unroll
            for (int i = 0; i < 8; ++i)
                #pragma unroll
                for (int j = 0; j < 8; ++j) acc[i][j] = fmaf(wv[i], ev[j], acc[i][j]);
        }
    }
    #pragma unroll
    for (int i = 0; i < 8; ++i) {
        int gj = gj0 + ty * 8 + i;
        float bias = bi[gj] + bh[gj];
        #pragma unroll
        for (int j = 0; j < 8; ++j) {
            int b = tx * 8 + j;
            xg[((((size_t)dir * L_ + t) * 64 + (b >> 1)) * 1024 + gj) * 2 + (b & 1)]
                = acc[i][j] + bias;
        }
    }
}

// ---------------------------------------------------------------------------
// Phase 1.5: transpose-pack recurrent weights.
// wtp[dir][k4][j] = float4{whh[j][4k4+0..3]}, j fastest (1024 rows).
// In the scan, a wave's 64 lanes (consecutive j) then load 64 consecutive
// float4 = 1KB fully-contiguous, eliminating the 8x L2 line over-fetch of
// the row-major layout (lanes at 1KB stride -> 64 lines per dwordx4).
// ---------------------------------------------------------------------------
__global__ void whh_pack(const float* __restrict__ whhf, const float* __restrict__ whhb,
                         float4* __restrict__ wtp)
{
    int gid = blockIdx.x * 256 + threadIdx.x;   // exactly 2*1024*64 threads
    int dir = gid >> 16;
    int rem = gid & 65535;
    int j = rem >> 6, k4 = rem & 63;
    const float* whh = dir ? whhb : whhf;
    float4 v = *(const float4*)(whh + (size_t)j * HID_ + k4 * 4);   // coalesced read
    wtp[((size_t)dir << 16) + (size_t)k4 * 1024 + j] = v;           // one-time scatter
}

// ---------------------------------------------------------------------------
// Phase 2: BiLSTM scan. Block = (dir, b-pair): 128 blocks x 1024 threads.
// Each thread owns ONE gate row j for 2 batch columns. Weights stream from
// the packed wtp layout: per k4, lanes j read contiguous 1KB -> full L2-line
// use. Floors: compute ~1.7us/step, L2 weight stream ~3.7us/step (16MB/XCD).
// ---------------------------------------------------------------------------
__global__ void __launch_bounds__(1024, 4) lstm_scan_d(
    const float* __restrict__ xg, const float4* __restrict__ wtp,
    float* __restrict__ xf, float* __restrict__ xb)
{
    int blk = blockIdx.x;
    int dir = blk >> 6;            // 0..1
    int bp  = blk & 63;            // b-pair index
    int j   = threadIdx.x;         // 0..1023 = gate row (gate = j>>8, hid = j&255)

    const float4* wt4 = wtp + ((size_t)dir << 16);   // [k4][j]
    float* xo = dir ? xb : xf;

    __shared__ float hs[HID_ * 2];      // [hid][bsub], 2KB; read as float4 (2 hid x 2 b)
    __shared__ float gs[1024 * 2];      // [gate][hid][bsub] = gate*512 + hid*2 + bs, 8KB

    if (j < 512) hs[j] = 0.f;
    float c = 0.f;                      // cell state for (hid=j>>1, bs=j&1), j<512 only
    __syncthreads();

    int gbase = (j >> 8) * 512 + (j & 255) * 2;   // gs write base for row j

    for (int t = 0; t < L_; ++t) {
        int slot = dir ? (L_ - 1 - t) : t;
        // xg gate preload (consumed after the k-loop -> fully hidden)
        const float* xbase = xg + (((size_t)dir * L_ + slot) * 64 + bp) * 2048;
        float2 gin = *(const float2*)(xbase + j * 2);

        float a0 = 0.f, a1 = 0.f;
        const float4* hp = (const float4*)hs;     // hp[q] = {h[2q]b0,h[2q]b1,h[2q+1]b0,h[2q+1]b1}
        #pragma unroll 8
        for (int k4 = 0; k4 < HID_ / 4; ++k4) {
            float4 wv = wt4[(size_t)k4 * 1024 + j];   // coalesced 1KB per wave-load
            float4 h0 = hp[k4 * 2];                   // broadcast reads (uniform per wave)
            float4 h1 = hp[k4 * 2 + 1];
            a0 = fmaf(wv.x, h0.x, a0); a1 = fmaf(wv.x, h0.y, a1);
            a0 = fmaf(wv.y, h0.z, a0); a1 = fmaf(wv.y, h0.w, a1);
            a0 = fmaf(wv.z, h1.x, a0); a1 = fmaf(wv.z, h1.y, a1);
            a0 = fmaf(wv.w, h1.z, a0); a1 = fmaf(wv.w, h1.w, a1);
        }
        *(float2*)(gs + gbase) = make_float2(a0 + gin.x, a1 + gin.y);
        __syncthreads();   // gs visible; all hs reads of this step complete

        if (j < 512) {     // j = hid*2 + bs
            float i_ = 1.f / (1.f + expf(-gs[j]));            // gate 0
            float f_ = 1.f / (1.f + expf(-gs[512 + j]));      // gate 1
            float g_ = tanhf(gs[1024 + j]);                   // gate 2
            float o_ = 1.f / (1.f + expf(-gs[1536 + j]));     // gate 3
            c = f_ * c + i_ * g_;
            float h = o_ * tanhf(c);
            hs[j] = h;
            int hid = j >> 1, bs = j & 1;
            xo[((size_t)slot * HID_ + hid) * B_ + bp * 2 + bs] = h;
        }
        __syncthreads();   // hs writes visible before next step's reads
    }
}

__global__ void x_add(const float* __restrict__ xf, const float* __restrict__ xb,
                      float* __restrict__ x)
{
    int idx = blockIdx.x * 256 + threadIdx.x;   // exactly L_*HID_*B_ threads
    x[idx] = xf[idx] + xb[idx];
}

// ---------------------------------------------------------------------------
// Phase 3: entity features, attention, primary capsules
// ---------------------------------------------------------------------------
__global__ void find_entity(const int* __restrict__ pos1, const int* __restrict__ pos2,
                            int* __restrict__ e)
{
    int b = threadIdx.x;
    int e1 = 0, e2 = 0;
    for (int l = L_ - 1; l >= 0; --l) if (pos1[b * L_ + l] == ENTITY) e1 = l;
    for (int l = L_ - 1; l >= 0; --l) if (pos2[b * L_ + l] == ENTITY) e2 = l;
    e[b] = e1; e[B_ + b] = e2;
}

__global__ void compute_he(const float* __restrict__ x, const int* __restrict__ e,
                           float* __restrict__ he)
{
    int j = blockIdx.x, b = threadIdx.x;
    int e1 = e[b], e2 = e[B_ + b];
    he[j * B_ + b] = x[((size_t)e1 * HID_ + j) * B_ + b] + x[((size_t)e2 * HID_ + j) * B_ + b];
}

__global__ void att_logits(const float* __restrict__ x, const float* __restrict__ he,
                           float* __restrict__ logits)
{
    int l = blockIdx.x, b = threadIdx.x;
    float acc = 0.f;
    for (int j = 0; j < HID_; ++j)
        acc = fmaf(x[((size_t)l * HID_ + j) * B_ + b], he[j * B_ + b], acc);
    logits[l * B_ + b] = acc;
}

__global__ void att_softmax(const float* __restrict__ logits, float* __restrict__ att)
{
    int b = threadIdx.x;
    float m = -1e30f;
    for (int l = 0; l < L_; ++l) m = fmaxf(m, logits[l * B_ + b]);
    float s = 0.f;
    for (int l = 0; l < L_; ++l) s += expf(logits[l * B_ + b] - m);
    float inv = 1.f / s;
    for (int l = 0; l < L_; ++l) att[l * B_ + b] = expf(logits[l * B_ + b] - m) * inv;
}

// primary capsules: u[i][b][c], squashed
__global__ void u_squash(const float* __restrict__ x, float* __restrict__ u)
{
    int i = blockIdx.x, b = threadIdx.x;
    int l = i >> 4, cap = i & 15;
    float vals[16]; float n2 = 0.f;
    #pragma unroll
    for (int c2 = 0; c2 < 16; ++c2) {
        float v = x[((size_t)l * HID_ + cap * 16 + c2) * B_ + b];
        vals[c2] = v; n2 = fmaf(v, v, n2);
    }
    float f = (n2 / (1.f + n2)) / sqrtf(n2 + 1e-9f);
    #pragma unroll
    for (int c2 = 0; c2 < 16; ++c2)
        u[((size_t)i * B_ + b) * 16 + c2] = vals[c2] * f;
}

// ---------------------------------------------------------------------------
// Phase 4: routing
// ---------------------------------------------------------------------------
__global__ void bb_init(const float* __restrict__ br, float* __restrict__ bb)
{
    int idx = blockIdx.x * 256 + threadIdx.x;   // exactly B_*NI*NCLASS threads
    bb[idx] = br[idx % (NI * NCLASS)];
}

__global__ void __launch_bounds__(320) s_pass(
    const float* __restrict__ u, const float* __restrict__ W,
    const float* __restrict__ bb, const float* __restrict__ att,
    float* __restrict__ partial)
{
    int ic = blockIdx.x, bt = blockIdx.y;
    int i0 = ic * 16, b0 = bt * 16;
    __shared__ float C[16][16][20];   // [bl][il][o], padded
    int tid = threadIdx.x;
    if (tid < 256) {
        int bl = tid >> 4, il = tid & 15;
        int b = b0 + bl, i = i0 + il;
        const float* bbp = bb + ((size_t)b * NI + i) * NCLASS;
        float m = bbp[0];
        #pragma unroll
        for (int o = 1; o < NCLASS; ++o) m = fmaxf(m, bbp[o]);
        float s = 0.f; float e[NCLASS];
        #pragma unroll
        for (int o = 0; o < NCLASS; ++o) { e[o] = expf(bbp[o] - m); s += e[o]; }
        float al = att[(i >> 4) * B_ + b] / s;
        #pragma unroll
        for (int o = 0; o < NCLASS; ++o) C[bl][il][o] = e[o] * al;
    }
    __syncthreads();
    if (tid >= OD) return;
    int od = tid, o = od >> 4;
    float acc[16];
    #pragma unroll
    for (int bl = 0; bl < 16; ++bl) acc[bl] = 0.f;
    for (int il = 0; il < 16; ++il) {
        int i = i0 + il;
        const float* wp = W + (size_t)i * 16 * OD + od;
        float w[16];
        #pragma unroll
        for (int c2 = 0; c2 < 16; ++c2) w[c2] = wp[c2 * OD];     // coalesced over od
        const float* up = u + ((size_t)i * B_ + b0) * 16;        // uniform -> s_load
        #pragma unroll
        for (int bl = 0; bl < 16; ++bl) {
            float uh = 0.f;
            #pragma unroll
            for (int c2 = 0; c2 < 16; ++c2) uh = fmaf(up[bl * 16 + c2], w[c2], uh);
            acc[bl] = fmaf(C[bl][il][o], uh, acc[bl]);
        }
    }
    #pragma unroll
    for (int bl = 0; bl < 16; ++bl)
        partial[((size_t)ic * B_ + b0 + bl) * OD + od] = acc[bl];
}

__global__ void s_reduce(const float* __restrict__ partial, float* __restrict__ s)
{
    int idx = blockIdx.x * 256 + threadIdx.x;   // exactly B_*OD threads
    int b = idx / OD, od = idx - b * OD;
    float acc = 0.f;
    for (int ic = 0; ic < 100; ++ic) acc += partial[((size_t)ic * B_ + b) * OD + od];
    s[idx] = acc;
}

__global__ void squash_v(const float* __restrict__ s, float* __restrict__ v,
                         float* __restrict__ out, int write_out)
{
    int idx = blockIdx.x * 256 + threadIdx.x;
    if (idx >= B_ * NCLASS) return;
    const float* sp = s + (size_t)idx * 16;     // b*304 + o*16 == idx*16
    float vals[16]; float n2 = 0.f;
    #pragma unroll
    for (int d = 0; d < 16; ++d) { vals[d] = sp[d]; n2 = fmaf(vals[d], vals[d], n2); }
    float f = (n2 / (1.f + n2)) / sqrtf(n2 + 1e-9f);
    float n2v = 0.f;
    #pragma unroll
    for (int d = 0; d < 16; ++d) {
        float vv = vals[d] * f;
        v[(size_t)idx * 16 + d] = vv;
        n2v = fmaf(vv, vv, n2v);
    }
    if (write_out) out[idx] = sqrtf(n2v + 1e-9f);
}

__global__ void __launch_bounds__(320) bb_pass(
    const float* __restrict__ u, const float* __restrict__ W,
    const float* __restrict__ v, float* __restrict__ bb)
{
    int ic = blockIdx.x, bt = blockIdx.y;
    int i0 = ic * 16, b0 = bt * 16;
    int tid = threadIdx.x;
    if (tid >= OD) return;
    int od = tid, o = od >> 4, d = od & 15;
    float vv[16];
    #pragma unroll
    for (int bl = 0; bl < 16; ++bl) vv[bl] = v[(size_t)(b0 + bl) * OD + od];
    for (int il = 0; il < 16; ++il) {
        int i = i0 + il;
        const float* wp = W + (size_t)i * 16 * OD + od;
        float w[16];
        #pragma unroll
        for (int c2 = 0; c2 < 16; ++c2) w[c2] = wp[c2 * OD];
        const float* up = u + ((size_t)i * B_ + b0) * 16;
        #pragma unroll
        for (int bl = 0; bl < 16; ++bl) {
            float uh = 0.f;
            #pragma unroll
            for (int c2 = 0; c2 < 16; ++c2) uh = fmaf(up[bl * 16 + c2], w[c2], uh);
            float p = uh * vv[bl];
            p += __shfl_xor(p, 1);
            p += __shfl_xor(p, 2);
            p += __shfl_xor(p, 4);
            p += __shfl_xor(p, 8);
            if (d == 0) bb[((size_t)(b0 + bl) * NI + i) * NCLASS + o] += p;
        }
    }
}

// ---------------------------------------------------------------------------
extern "C" void kernel_launch(void* const* d_in, const int* in_sizes, int n_in,
                              void* d_out, int out_size, void* d_ws, size_t ws_size,
                              hipStream_t stream)
{
    (void)in_sizes; (void)n_in; (void)out_size; (void)ws_size;
    const int*   word = (const int*)d_in[0];
    const int*   tag  = (const int*)d_in[1];
    const int*   pos1 = (const int*)d_in[2];
    const int*   pos2 = (const int*)d_in[3];
    const float* we   = (const float*)d_in[4];
    const float* te   = (const float*)d_in[5];
    const float* p1e  = (const float*)d_in[6];
    const float* p2e  = (const float*)d_in[7];
    const float* wihf = (const float*)d_in[8];
    const float* whhf = (const float*)d_in[9];
    const float* bihf = (const float*)d_in[10];
    const float* bhhf = (const float*)d_in[11];
    const float* wihb = (const float*)d_in[12];
    const float* whhb = (const float*)d_in[13];
    const float* bihb = (const float*)d_in[14];
    const float* bhhb = (const float*)d_in[15];
    const float* Wc   = (const float*)d_in[16];
    const float* br   = (const float*)d_in[17];

    float* wsp    = (float*)d_ws;
    float* emb    = wsp;                       //  2,048,000
    float* xg     = wsp + 2048000;             // 26,214,400
    float* xf     = xg + 26214400;             //  3,276,800
    float* xb     = xf + 3276800;              //  3,276,800
    float* he     = xb + 3276800;              //     32,768
    float* logits = he + 32768;                //     12,800
    float* att    = logits + 12800;            //     12,800
    int*   e      = (int*)(att + 12800);       //        256 ints
    // packed recurrent weights alias the (dead-after-gemm_xg) emb region
    float4* wtp = (float4*)emb;                //  524,288 floats (2 MB)
    // post-scan buffers alias the (dead-after-scan) xg region
    float* x    = xg;                          //  3,276,800
    float* u    = xg + 3276800;                //  3,276,800
    float* bb   = xg + 6553600;                //  3,891,200
    float* part = xg + 10444800;               //  3,891,200
    float* s    = xg + 14336000;               //     38,912
    float* v    = s + 38912;                   //     38,912
    float* out  = (float*)d_out;

    emb_gather<<<8000, 256, 0, stream>>>(word, tag, pos1, pos2, we, te, p1e, p2e, emb);
    gemm_xg<<<dim3(8, 100, 2), 256, 0, stream>>>(emb, wihf, bihf, bhhf, wihb, bihb, bhhb, xg);
    whh_pack<<<512, 256, 0, stream>>>(whhf, whhb, wtp);
    lstm_scan_d<<<128, 1024, 0, stream>>>(xg, wtp, xf, xb);
    x_add<<<12800, 256, 0, stream>>>(xf, xb, x);
    find_entity<<<1, 128, 0, stream>>>(pos1, pos2, e);
    compute_he<<<256, 128, 0, stream>>>(x, e, he);
    att_logits<<<100, 128, 0, stream>>>(x, he, logits);
    att_softmax<<<1, 128, 0, stream>>>(logits, att);
    u_squash<<<1600, 128, 0, stream>>>(x, u);
    bb_init<<<15200, 256, 0, stream>>>(br, bb);
    for (int it = 0; it < 3; ++it) {
        s_pass<<<dim3(100, 8), 320, 0, stream>>>(u, Wc, bb, att, part);
        s_reduce<<<152, 256, 0, stream>>>(part, s);
        squash_v<<<10, 256, 0, stream>>>(s, v, out, (it == 2) ? 1 : 0);
        if (it < 2) bb_pass<<<dim3(100, 8), 320, 0, stream>>>(u, Wc, v, bb);
    }
}